// Round 7
// baseline (460.009 us; speedup 1.0000x reference)
//
#include <hip/hip_runtime.h>
#include <hip/hip_bf16.h>

#define NNODES 100000
#define NEDGES 1600000
#define DF 128
#define NGRAPH 256
#define SCAN_CHUNK 2048
#define NB_SCAN ((NNODES + SCAN_CHUNK - 1) / SCAN_CHUNK)

typedef __attribute__((ext_vector_type(8))) short short8;
typedef __attribute__((ext_vector_type(4))) float f32x4;

// ---------------- degree count (in-degree over real edges) ----------------
__global__ void deg_kernel(const int* __restrict__ dst, int* __restrict__ deg, int E) {
    int e = blockIdx.x * 256 + threadIdx.x;
    if (e < E) atomicAdd(&deg[dst[e]], 1);
}

// dinv[v] = rsqrt(deg[v] + 1)   (+1 = self loop; always >= 1)
__global__ void dinv_kernel(const int* __restrict__ deg, float* __restrict__ dinv, int n) {
    int v = blockIdx.x * 256 + threadIdx.x;
    if (v < n) dinv[v] = rsqrtf((float)deg[v] + 1.0f);
}

// ---------------- hierarchical scan of (deg[v]+1) -> offs[0..n], cursor ----------------
__global__ void scan1_kernel(const int* __restrict__ deg, int* __restrict__ psum, int n) {
    __shared__ int lds[256];
    int t = threadIdx.x;
    int base = blockIdx.x * SCAN_CHUNK + t * 8;
    int s = 0;
    #pragma unroll
    for (int i = 0; i < 8; i++) { int idx = base + i; if (idx < n) s += deg[idx] + 1; }
    lds[t] = s;
    __syncthreads();
    for (int off = 128; off > 0; off >>= 1) {
        if (t < off) lds[t] += lds[t + off];
        __syncthreads();
    }
    if (t == 0) psum[blockIdx.x] = lds[0];
}

__global__ void scan2_kernel(int* __restrict__ psum, int* __restrict__ offs, int nb, int n) {
    __shared__ int lds[64];
    int t = threadIdx.x;  // 64 threads
    int v = (t < nb) ? psum[t] : 0;
    lds[t] = v;
    __syncthreads();
    for (int off = 1; off < 64; off <<= 1) {
        int x = lds[t];
        int add = (t >= off) ? lds[t - off] : 0;
        __syncthreads();
        lds[t] = x + add;
        __syncthreads();
    }
    if (t < nb) psum[t] = lds[t] - v;  // exclusive prefix of block sums
    if (t == 63) offs[n] = lds[63];    // grand total
}

// scan3: local exclusive scan + block prefix; writes offs[], cursor[] (slot0 reserved),
// and the self-loop record csrc[offs[v]] = v (monotonic, streaming-ish writes).
__global__ void scan3_kernel(const int* __restrict__ deg, const int* __restrict__ psum,
                             int* __restrict__ offs, int* __restrict__ cursor,
                             int* __restrict__ csrc, int n) {
    __shared__ int lds[256];
    int t = threadIdx.x;
    int base = blockIdx.x * SCAN_CHUNK + t * 8;
    int dv[8];
    int s = 0;
    #pragma unroll
    for (int i = 0; i < 8; i++) {
        int idx = base + i;
        dv[i] = (idx < n) ? deg[idx] + 1 : 0;
        s += dv[i];
    }
    lds[t] = s;
    __syncthreads();
    for (int off = 1; off < 256; off <<= 1) {
        int x = lds[t];
        int add = (t >= off) ? lds[t - off] : 0;
        __syncthreads();
        lds[t] = x + add;
        __syncthreads();
    }
    int run = psum[blockIdx.x] + lds[t] - s;
    #pragma unroll
    for (int i = 0; i < 8; i++) {
        int idx = base + i;
        if (idx < n) {
            offs[idx] = run;
            cursor[idx] = run + 1;                          // slot 0 = self loop
            __builtin_nontemporal_store(idx, csrc + run);   // self record
            run += dv[i];
        }
    }
}

// scatter real edges: 4 edges/thread, src-only 4B nontemporal scatter
__global__ void fill_edges(const int* __restrict__ src, const int* __restrict__ dst,
                           int* __restrict__ cursor, int* __restrict__ csrc, int E) {
    int e0 = (blockIdx.x * 256 + threadIdx.x) * 4;
    if (e0 + 4 <= E) {
        int4 s4 = *(const int4*)(src + e0);
        int4 d4 = *(const int4*)(dst + e0);
        int p0 = atomicAdd(&cursor[d4.x], 1);
        int p1 = atomicAdd(&cursor[d4.y], 1);
        int p2 = atomicAdd(&cursor[d4.z], 1);
        int p3 = atomicAdd(&cursor[d4.w], 1);
        __builtin_nontemporal_store(s4.x, csrc + p0);
        __builtin_nontemporal_store(s4.y, csrc + p1);
        __builtin_nontemporal_store(s4.z, csrc + p2);
        __builtin_nontemporal_store(s4.w, csrc + p3);
    } else {
        for (int e = e0; e < E; e++) {
            int s = src[e], d0 = dst[e];
            int pos = atomicAdd(&cursor[d0], 1);
            __builtin_nontemporal_store(s, csrc + pos);
        }
    }
}

// RNE pack: two f32 -> bf16x2 (lo = a, hi = b)
__device__ __forceinline__ unsigned int pack_bf16x2(float a, float b) {
    unsigned int ua = __float_as_uint(a);
    unsigned int ub = __float_as_uint(b);
    ua += 0x7fffu + ((ua >> 16) & 1u);
    ub += 0x7fffu + ((ub >> 16) & 1u);
    return (ua >> 16) | (ub & 0xffff0000u);
}

// split f32 -> (hi bf16, lo bf16): w ~= hi + lo, error ~2^-17 relative
__device__ __forceinline__ void split_bf16(float w, unsigned short& h, unsigned short& l) {
    unsigned int uw = __float_as_uint(w);
    unsigned int hb = uw + 0x7fffu + ((uw >> 16) & 1u);
    h = (unsigned short)(hb >> 16);
    float rem = w - __uint_as_float((unsigned int)h << 16);
    unsigned int ur = __float_as_uint(rem);
    unsigned int lb = ur + 0x7fffu + ((ur >> 16) & 1u);
    l = (unsigned short)(lb >> 16);
}

// ---------------- W prep: frag-major split-bf16 layout ----------------
__global__ void wprep_kernel(const float* __restrict__ W, unsigned short* __restrict__ Wh,
                             unsigned short* __restrict__ Wl) {
    int id = blockIdx.x * 256 + threadIdx.x;  // 0..2047
    if (id >= 2048) return;
    int lane = id & 63, tq = id >> 6;
    int t = tq >> 2, q = tq & 3;
    int n = 16 * t + (lane & 15);
    int kbase = 32 * q + 8 * (lane >> 4);
    unsigned short h[8], l[8];
    #pragma unroll
    for (int i = 0; i < 8; i++) {
        split_bf16(W[(kbase + i) * DF + n], h[i], l[i]);
    }
    uint4 hv, lv;
    hv.x = h[0] | ((unsigned int)h[1] << 16); hv.y = h[2] | ((unsigned int)h[3] << 16);
    hv.z = h[4] | ((unsigned int)h[5] << 16); hv.w = h[6] | ((unsigned int)h[7] << 16);
    lv.x = l[0] | ((unsigned int)l[1] << 16); lv.y = l[2] | ((unsigned int)l[3] << 16);
    lv.z = l[4] | ((unsigned int)l[5] << 16); lv.w = l[6] | ((unsigned int)l[7] << 16);
    ((uint4*)Wh)[id] = hv;
    ((uint4*)Wl)[id] = lv;
}

// ---------------- MFMA GEMM: C_bf16[n,128] = A_f32[n,128] @ W[128,128] -------------
__global__ void gemm_mfma(const float* __restrict__ A, const unsigned short* __restrict__ Wh,
                          const unsigned short* __restrict__ Wl, unsigned int* __restrict__ C,
                          int nrows) {
    int tid = threadIdx.x;
    int wv = tid >> 6, lane = tid & 63;
    int c16 = lane & 15, g = lane >> 4;
    int row = blockIdx.x * 64 + wv * 16 + c16;
    int rowc = min(row, nrows - 1);
    const float4* A4 = (const float4*)A;
    const short8* Wh8 = (const short8*)Wh;
    const short8* Wl8 = (const short8*)Wl;
    f32x4 acc[8];
    #pragma unroll
    for (int t = 0; t < 8; t++) acc[t] = (f32x4){0.f, 0.f, 0.f, 0.f};
    #pragma unroll
    for (int q = 0; q < 4; q++) {
        float4 a0 = A4[(size_t)rowc * 32 + q * 8 + g * 2];
        float4 a1 = A4[(size_t)rowc * 32 + q * 8 + g * 2 + 1];
        float av[8] = {a0.x, a0.y, a0.z, a0.w, a1.x, a1.y, a1.z, a1.w};
        short8 ah, al;
        #pragma unroll
        for (int i = 0; i < 8; i++) {
            unsigned short hs, ls;
            split_bf16(av[i], hs, ls);
            ah[i] = (short)hs;
            al[i] = (short)ls;
        }
        #pragma unroll
        for (int t = 0; t < 8; t++) {
            short8 wh = Wh8[(t * 4 + q) * 64 + lane];
            short8 wl = Wl8[(t * 4 + q) * 64 + lane];
            acc[t] = __builtin_amdgcn_mfma_f32_16x16x32_bf16(wh, ah, acc[t], 0, 0, 0);
            acc[t] = __builtin_amdgcn_mfma_f32_16x16x32_bf16(wh, al, acc[t], 0, 0, 0);
            acc[t] = __builtin_amdgcn_mfma_f32_16x16x32_bf16(wl, ah, acc[t], 0, 0, 0);
        }
    }
    if (row < nrows) {
        uint2* C2 = (uint2*)C;
        #pragma unroll
        for (int t = 0; t < 8; t++) {
            uint2 w;
            w.x = pack_bf16x2(acc[t][0], acc[t][1]);
            w.y = pack_bf16x2(acc[t][2], acc[t][3]);
            C2[(size_t)row * 32 + t * 4 + g] = w;
        }
    }
}

// ---------------- CSR aggregation: Out[v] = epilogue(sum dinv[s]*dinv[v]*H[s]) -------
// One 64-lane wave per node; H bf16 (row=256B); lane owns feats {2l,2l+1}.
// Records (src only, 4B) preloaded coalesced + shfl broadcast; norm recomputed
// from L2-resident dinv (wave-uniform load, hidden under x8-unrolled gathers).
template <int BIAS_RELU>
__global__ void agg_kernel(const int* __restrict__ roff, const int* __restrict__ csrc,
                           const float* __restrict__ dinv, const unsigned int* __restrict__ Hb,
                           const float* __restrict__ bias, float* __restrict__ Out) {
    int tid = threadIdx.x;
    int wv = tid >> 6, lane = tid & 63;
    size_t v = (size_t)blockIdx.x * 4 + wv;
    int b = roff[v], e = roff[v + 1];
    float dvv = dinv[v];
    float2 acc = {0.f, 0.f};
    for (int base = b; base < e; base += 64) {
        int idx = base + lane;
        if (idx >= e) idx = e - 1;       // clamped dup, never consumed
        int rec = csrc[idx];             // one coalesced 256B record load
        int kmax = min(64, e - base);
        int k = 0;
        for (; k + 8 <= kmax; k += 8) {
            int s[8];
            float nm[8];
            unsigned int u[8];
            #pragma unroll
            for (int j = 0; j < 8; j++) {
                s[j] = __shfl(rec, k + j, 64);
                nm[j] = dinv[s[j]];                       // wave-uniform, L2-resident
                u[j] = Hb[(size_t)s[j] * 64 + lane];      // 256B row gather
            }
            #pragma unroll
            for (int j = 0; j < 8; j++) {
                float sc = nm[j] * dvv;
                acc.x += sc * __uint_as_float(u[j] << 16);
                acc.y += sc * __uint_as_float(u[j] & 0xffff0000u);
            }
        }
        for (; k < kmax; k++) {
            int s0 = __shfl(rec, k, 64);
            float sc = dinv[s0] * dvv;
            unsigned int u0 = Hb[(size_t)s0 * 64 + lane];
            acc.x += sc * __uint_as_float(u0 << 16);
            acc.y += sc * __uint_as_float(u0 & 0xffff0000u);
        }
    }
    if (BIAS_RELU) {
        float2 bb = ((const float2*)bias)[lane];
        acc.x = fmaxf(acc.x + bb.x, 0.f);
        acc.y = fmaxf(acc.y + bb.y, 0.f);
    }
    ((float2*)Out)[v * 64 + lane] = acc;
}

// ---------------- segmented mean-pool (batch sorted) ----------------
__global__ void pool_kernel(const float* __restrict__ H, const int* __restrict__ batch,
                            float* __restrict__ gsum, float* __restrict__ gcnt, int n) {
    __shared__ int bl[128];
    int d = threadIdx.x;
    int base = blockIdx.x * 128;
    int cnt_here = min(128, n - base);
    if (cnt_here <= 0) return;
    if (d < cnt_here) bl[d] = batch[base + d];
    __syncthreads();
    float acc = 0.f;
    int cg = -1, c = 0;
    for (int i = 0; i < cnt_here; i++) {
        int g = bl[i];
        if (g != cg) {
            if (cg >= 0) {
                atomicAdd(&gsum[cg * DF + d], acc);
                if (d == 0) atomicAdd(&gcnt[cg], (float)c);
            }
            acc = 0.f; c = 0; cg = g;
        }
        acc += H[(size_t)(base + i) * DF + d];
        c++;
    }
    if (cg >= 0) {
        atomicAdd(&gsum[cg * DF + d], acc);
        if (d == 0) atomicAdd(&gcnt[cg], (float)c);
    }
}

// ---------------- final: out[g] = dot(gsum[g]/cnt + b2, Wm) + bm ----------------
__global__ void final_kernel(const float* __restrict__ gsum, const float* __restrict__ gcnt,
                             const float* __restrict__ b2, const float* __restrict__ Wm,
                             const float* __restrict__ bm, float* __restrict__ out) {
    __shared__ float red[2];
    int g = blockIdx.x, d = threadIdx.x;
    float cnt = fmaxf(gcnt[g], 1.0f);
    float v = (gsum[g * DF + d] / cnt + b2[d]) * Wm[d];
    for (int off = 32; off > 0; off >>= 1) v += __shfl_down(v, off, 64);
    if ((d & 63) == 0) red[d >> 6] = v;
    __syncthreads();
    if (d == 0) out[g] = red[0] + red[1] + bm[0];
}

extern "C" void kernel_launch(void* const* d_in, const int* in_sizes, int n_in,
                              void* d_out, int out_size, void* d_ws, size_t ws_size,
                              hipStream_t stream) {
    const float* x   = (const float*)d_in[0];
    const int*   ei  = (const int*)d_in[1];   // [2, E] flat: first E = src, next E = dst
    const int*   bat = (const int*)d_in[2];
    const float* W1  = (const float*)d_in[3];
    const float* b1  = (const float*)d_in[4];
    const float* W2  = (const float*)d_in[5];
    const float* b2  = (const float*)d_in[6];
    const float* Wm  = (const float*)d_in[7];
    const float* bm  = (const float*)d_in[8];
    float* out = (float*)d_out;

    const int N = NNODES, E = NEDGES, G = NGRAPH;
    const int* src = ei;
    const int* dst = ei + E;

    // workspace carve
    char* base = (char*)d_ws;
    size_t o = 0;
    auto alloc = [&](size_t bytes) { size_t p = o; o = (o + bytes + 255) & ~(size_t)255; return p; };
    int*   deg    = (int*)(base + alloc((size_t)N * 4));
    int*   cursor = (int*)(base + alloc((size_t)N * 4));
    int*   offs   = (int*)(base + alloc((size_t)(N + 1) * 4));
    float* dinv   = (float*)(base + alloc((size_t)N * 4));
    int*   psum   = (int*)(base + alloc((size_t)NB_SCAN * 4));
    int*   csrc   = (int*)(base + alloc((size_t)(E + N) * 4));
    unsigned int* bufH = (unsigned int*)(base + alloc((size_t)N * DF * 2));  // bf16 H
    float* bufB   = (float*)(base + alloc((size_t)N * DF * 4));
    float* gsum   = (float*)(base + alloc((size_t)G * DF * 4));
    float* gcnt   = (float*)(base + alloc((size_t)G * 4));
    unsigned short* wh1 = (unsigned short*)(base + alloc(2048 * 16));
    unsigned short* wl1 = (unsigned short*)(base + alloc(2048 * 16));
    unsigned short* wh2 = (unsigned short*)(base + alloc(2048 * 16));
    unsigned short* wl2 = (unsigned short*)(base + alloc(2048 * 16));
    (void)ws_size;

    hipMemsetAsync(deg, 0, (size_t)N * 4, stream);
    hipMemsetAsync(gsum, 0, (size_t)G * DF * 4, stream);
    hipMemsetAsync(gcnt, 0, (size_t)G * 4, stream);

    // CSR build
    deg_kernel<<<(E + 255) / 256, 256, 0, stream>>>(dst, deg, E);
    dinv_kernel<<<(N + 255) / 256, 256, 0, stream>>>(deg, dinv, N);
    scan1_kernel<<<NB_SCAN, 256, 0, stream>>>(deg, psum, N);
    scan2_kernel<<<1, 64, 0, stream>>>(psum, offs, NB_SCAN, N);
    scan3_kernel<<<NB_SCAN, 256, 0, stream>>>(deg, psum, offs, cursor, csrc, N);
    fill_edges<<<(E / 4 + 255) / 256, 256, 0, stream>>>(src, dst, cursor, csrc, E);

    // W prep (tiny)
    wprep_kernel<<<8, 256, 0, stream>>>(W1, wh1, wl1);
    wprep_kernel<<<8, 256, 0, stream>>>(W2, wh2, wl2);

    // layer 1: bufH = bf16(x @ W1) ; bufB = relu(A_hat * bufH + b1)
    gemm_mfma<<<(N + 63) / 64, 256, 0, stream>>>(x, wh1, wl1, bufH, N);
    agg_kernel<1><<<N / 4, 256, 0, stream>>>(offs, csrc, dinv, bufH, b1, bufB);

    // layer 2: bufH = bf16(bufB @ W2) ; bufB = A_hat * bufH
    gemm_mfma<<<(N + 63) / 64, 256, 0, stream>>>(bufB, wh2, wl2, bufH, N);
    agg_kernel<0><<<N / 4, 256, 0, stream>>>(offs, csrc, dinv, bufH, nullptr, bufB);

    // pool + final
    pool_kernel<<<(N + 127) / 128, 128, 0, stream>>>(bufB, bat, gsum, gcnt, N);
    final_kernel<<<G, 128, 0, stream>>>(gsum, gcnt, b2, Wm, bm, out);
}

// Round 8
// 450.486 us; speedup vs baseline: 1.0211x; 1.0211x over previous
//
#include <hip/hip_runtime.h>
#include <hip/hip_bf16.h>

#define NNODES 100000
#define NEDGES 1600000
#define DF 128
#define NGRAPH 256
#define SCAN_CHUNK 2048
#define NB_SCAN ((NNODES + SCAN_CHUNK - 1) / SCAN_CHUNK)

typedef __attribute__((ext_vector_type(8))) short short8;
typedef __attribute__((ext_vector_type(4))) float f32x4;

// ---------------- degree count (in-degree over real edges) ----------------
__global__ void deg_kernel(const int* __restrict__ dst, int* __restrict__ deg, int E) {
    int e = blockIdx.x * 256 + threadIdx.x;
    if (e < E) atomicAdd(&deg[dst[e]], 1);
}

// ---------------- hierarchical scan of (deg[v]+1); also emits dinv ----------------
__global__ void scan1_kernel(const int* __restrict__ deg, int* __restrict__ psum,
                             float* __restrict__ dinv, int n) {
    __shared__ int lds[256];
    int t = threadIdx.x;
    int base = blockIdx.x * SCAN_CHUNK + t * 8;
    int s = 0;
    #pragma unroll
    for (int i = 0; i < 8; i++) {
        int idx = base + i;
        if (idx < n) {
            int d = deg[idx];
            dinv[idx] = rsqrtf((float)d + 1.0f);
            s += d + 1;
        }
    }
    lds[t] = s;
    __syncthreads();
    for (int off = 128; off > 0; off >>= 1) {
        if (t < off) lds[t] += lds[t + off];
        __syncthreads();
    }
    if (t == 0) psum[blockIdx.x] = lds[0];
}

__global__ void scan2_kernel(int* __restrict__ psum, int* __restrict__ offs, int nb, int n) {
    __shared__ int lds[64];
    int t = threadIdx.x;  // 64 threads
    int v = (t < nb) ? psum[t] : 0;
    lds[t] = v;
    __syncthreads();
    for (int off = 1; off < 64; off <<= 1) {
        int x = lds[t];
        int add = (t >= off) ? lds[t - off] : 0;
        __syncthreads();
        lds[t] = x + add;
        __syncthreads();
    }
    if (t < nb) psum[t] = lds[t] - v;  // exclusive prefix of block sums
    if (t == 63) offs[n] = lds[63];    // grand total
}

// scan3: local exclusive scan + block prefix; writes offs[], cursor[] (slot0 = self),
// and the self-loop record csrc[offs[v]] = v.
__global__ void scan3_kernel(const int* __restrict__ deg, const int* __restrict__ psum,
                             int* __restrict__ offs, int* __restrict__ cursor,
                             int* __restrict__ csrc, int n) {
    __shared__ int lds[256];
    int t = threadIdx.x;
    int base = blockIdx.x * SCAN_CHUNK + t * 8;
    int dv[8];
    int s = 0;
    #pragma unroll
    for (int i = 0; i < 8; i++) {
        int idx = base + i;
        dv[i] = (idx < n) ? deg[idx] + 1 : 0;
        s += dv[i];
    }
    lds[t] = s;
    __syncthreads();
    for (int off = 1; off < 256; off <<= 1) {
        int x = lds[t];
        int add = (t >= off) ? lds[t - off] : 0;
        __syncthreads();
        lds[t] = x + add;
        __syncthreads();
    }
    int run = psum[blockIdx.x] + lds[t] - s;
    #pragma unroll
    for (int i = 0; i < 8; i++) {
        int idx = base + i;
        if (idx < n) {
            offs[idx] = run;
            cursor[idx] = run + 1;   // slot 0 = self loop
            csrc[run] = idx;         // self record
            run += dv[i];
        }
    }
}

// scatter real edges: 1 edge/thread, plain 4B store (L2 absorbs/merges)
__global__ void fill_edges(const int* __restrict__ src, const int* __restrict__ dst,
                           int* __restrict__ cursor, int* __restrict__ csrc, int E) {
    int e = blockIdx.x * 256 + threadIdx.x;
    if (e >= E) return;
    int s = src[e], d0 = dst[e];
    int pos = atomicAdd(&cursor[d0], 1);
    csrc[pos] = s;
}

// RNE pack: two f32 -> bf16x2 (lo = a, hi = b)
__device__ __forceinline__ unsigned int pack_bf16x2(float a, float b) {
    unsigned int ua = __float_as_uint(a);
    unsigned int ub = __float_as_uint(b);
    ua += 0x7fffu + ((ua >> 16) & 1u);
    ub += 0x7fffu + ((ub >> 16) & 1u);
    return (ua >> 16) | (ub & 0xffff0000u);
}

// split f32 -> (hi bf16, lo bf16): w ~= hi + lo, error ~2^-17 relative
__device__ __forceinline__ void split_bf16(float w, unsigned short& h, unsigned short& l) {
    unsigned int uw = __float_as_uint(w);
    unsigned int hb = uw + 0x7fffu + ((uw >> 16) & 1u);
    h = (unsigned short)(hb >> 16);
    float rem = w - __uint_as_float((unsigned int)h << 16);
    unsigned int ur = __float_as_uint(rem);
    unsigned int lb = ur + 0x7fffu + ((ur >> 16) & 1u);
    l = (unsigned short)(lb >> 16);
}

// ---------------- W prep: frag-major split-bf16 layout ----------------
__global__ void wprep_kernel(const float* __restrict__ W, unsigned short* __restrict__ Wh,
                             unsigned short* __restrict__ Wl) {
    int id = blockIdx.x * 256 + threadIdx.x;  // 0..2047
    if (id >= 2048) return;
    int lane = id & 63, tq = id >> 6;
    int t = tq >> 2, q = tq & 3;
    int n = 16 * t + (lane & 15);
    int kbase = 32 * q + 8 * (lane >> 4);
    unsigned short h[8], l[8];
    #pragma unroll
    for (int i = 0; i < 8; i++) {
        split_bf16(W[(kbase + i) * DF + n], h[i], l[i]);
    }
    uint4 hv, lv;
    hv.x = h[0] | ((unsigned int)h[1] << 16); hv.y = h[2] | ((unsigned int)h[3] << 16);
    hv.z = h[4] | ((unsigned int)h[5] << 16); hv.w = h[6] | ((unsigned int)h[7] << 16);
    lv.x = l[0] | ((unsigned int)l[1] << 16); lv.y = l[2] | ((unsigned int)l[3] << 16);
    lv.z = l[4] | ((unsigned int)l[5] << 16); lv.w = l[6] | ((unsigned int)l[7] << 16);
    ((uint4*)Wh)[id] = hv;
    ((uint4*)Wl)[id] = lv;
}

// ---------------- MFMA GEMM: C_bf16[n,128] = dinv[n] * (A[n,128] @ W[128,128]) --------
// ABF16=0: A fp32, split into ah+al, 3 MFMAs. ABF16=1: A bf16, 2 MFMAs.
// W-frag = MxK operand, node-rows = KxN operand -> D col = node row,
// regs = 4 consecutive features -> lane-local bf16 pack. 4 waves/block, no LDS.
template <int ABF16>
__global__ void gemm_mfma(const void* __restrict__ Ap, const unsigned short* __restrict__ Wh,
                          const unsigned short* __restrict__ Wl, const float* __restrict__ dinv,
                          unsigned int* __restrict__ C, int nrows) {
    int tid = threadIdx.x;
    int wv = tid >> 6, lane = tid & 63;
    int c16 = lane & 15, g = lane >> 4;
    int row = blockIdx.x * 64 + wv * 16 + c16;
    int rowc = min(row, nrows - 1);
    const short8* Wh8 = (const short8*)Wh;
    const short8* Wl8 = (const short8*)Wl;
    f32x4 acc[8];
    #pragma unroll
    for (int t = 0; t < 8; t++) acc[t] = (f32x4){0.f, 0.f, 0.f, 0.f};
    #pragma unroll
    for (int q = 0; q < 4; q++) {
        short8 ah, al;
        if (ABF16) {
            ah = ((const short8*)Ap)[(size_t)rowc * 16 + q * 4 + g];
        } else {
            const float4* A4 = (const float4*)Ap;
            float4 a0 = A4[(size_t)rowc * 32 + q * 8 + g * 2];
            float4 a1 = A4[(size_t)rowc * 32 + q * 8 + g * 2 + 1];
            float av[8] = {a0.x, a0.y, a0.z, a0.w, a1.x, a1.y, a1.z, a1.w};
            #pragma unroll
            for (int i = 0; i < 8; i++) {
                unsigned short hs, ls;
                split_bf16(av[i], hs, ls);
                ah[i] = (short)hs;
                al[i] = (short)ls;
            }
        }
        #pragma unroll
        for (int t = 0; t < 8; t++) {
            short8 wh = Wh8[(t * 4 + q) * 64 + lane];
            short8 wl = Wl8[(t * 4 + q) * 64 + lane];
            acc[t] = __builtin_amdgcn_mfma_f32_16x16x32_bf16(wh, ah, acc[t], 0, 0, 0);
            if (!ABF16) acc[t] = __builtin_amdgcn_mfma_f32_16x16x32_bf16(wh, al, acc[t], 0, 0, 0);
            acc[t] = __builtin_amdgcn_mfma_f32_16x16x32_bf16(wl, ah, acc[t], 0, 0, 0);
        }
    }
    if (row < nrows) {
        float dvr = dinv[row];
        uint2* C2 = (uint2*)C;
        #pragma unroll
        for (int t = 0; t < 8; t++) {
            uint2 w;
            w.x = pack_bf16x2(acc[t][0] * dvr, acc[t][1] * dvr);
            w.y = pack_bf16x2(acc[t][2] * dvr, acc[t][3] * dvr);
            C2[(size_t)row * 32 + t * 4 + g] = w;
        }
    }
}

// ---------------- CSR aggregation: out[v] = epi(dinv[v] * sum_s Hb[s]) ----------------
// Hb rows are pre-scaled by dinv[s] in the GEMM epilogue -> NO per-edge norm work.
// One 64-lane wave per node; H bf16 (row=256B); lane owns feats {2l,2l+1}.
template <int BIAS_RELU, int OUT16>
__global__ void agg_kernel(const int* __restrict__ roff, const int* __restrict__ csrc,
                           const float* __restrict__ dinv, const unsigned int* __restrict__ Hb,
                           const float* __restrict__ bias, void* __restrict__ Out) {
    int tid = threadIdx.x;
    int wv = tid >> 6, lane = tid & 63;
    size_t v = (size_t)blockIdx.x * 4 + wv;
    int b = roff[v], e = roff[v + 1];
    float2 acc = {0.f, 0.f};
    for (int base = b; base < e; base += 64) {
        int idx = base + lane;
        if (idx >= e) idx = e - 1;       // clamped dup, never consumed
        int rec = csrc[idx];             // one coalesced 256B record load
        int kmax = min(64, e - base);
        int k = 0;
        for (; k + 8 <= kmax; k += 8) {
            unsigned int u[8];
            #pragma unroll
            for (int j = 0; j < 8; j++) {
                int s = __shfl(rec, k + j, 64);
                u[j] = Hb[(size_t)s * 64 + lane];      // 256B row gather
            }
            #pragma unroll
            for (int j = 0; j < 8; j++) {
                acc.x += __uint_as_float(u[j] << 16);
                acc.y += __uint_as_float(u[j] & 0xffff0000u);
            }
        }
        for (; k < kmax; k++) {
            int s0 = __shfl(rec, k, 64);
            unsigned int u0 = Hb[(size_t)s0 * 64 + lane];
            acc.x += __uint_as_float(u0 << 16);
            acc.y += __uint_as_float(u0 & 0xffff0000u);
        }
    }
    float dvv = dinv[v];
    acc.x *= dvv;
    acc.y *= dvv;
    if (BIAS_RELU) {
        float2 bb = ((const float2*)bias)[lane];
        acc.x = fmaxf(acc.x + bb.x, 0.f);
        acc.y = fmaxf(acc.y + bb.y, 0.f);
    }
    if (OUT16) {
        ((unsigned int*)Out)[v * 64 + lane] = pack_bf16x2(acc.x, acc.y);
    } else {
        ((float2*)Out)[v * 64 + lane] = acc;
    }
}

// ---------------- segmented mean-pool (batch sorted) ----------------
__global__ void pool_kernel(const float* __restrict__ H, const int* __restrict__ batch,
                            float* __restrict__ gsum, float* __restrict__ gcnt, int n) {
    __shared__ int bl[128];
    int d = threadIdx.x;
    int base = blockIdx.x * 128;
    int cnt_here = min(128, n - base);
    if (cnt_here <= 0) return;
    if (d < cnt_here) bl[d] = batch[base + d];
    __syncthreads();
    float acc = 0.f;
    int cg = -1, c = 0;
    for (int i = 0; i < cnt_here; i++) {
        int g = bl[i];
        if (g != cg) {
            if (cg >= 0) {
                atomicAdd(&gsum[cg * DF + d], acc);
                if (d == 0) atomicAdd(&gcnt[cg], (float)c);
            }
            acc = 0.f; c = 0; cg = g;
        }
        acc += H[(size_t)(base + i) * DF + d];
        c++;
    }
    if (cg >= 0) {
        atomicAdd(&gsum[cg * DF + d], acc);
        if (d == 0) atomicAdd(&gcnt[cg], (float)c);
    }
}

// ---------------- final: out[g] = dot(gsum[g]/cnt + b2, Wm) + bm ----------------
__global__ void final_kernel(const float* __restrict__ gsum, const float* __restrict__ gcnt,
                             const float* __restrict__ b2, const float* __restrict__ Wm,
                             const float* __restrict__ bm, float* __restrict__ out) {
    __shared__ float red[2];
    int g = blockIdx.x, d = threadIdx.x;
    float cnt = fmaxf(gcnt[g], 1.0f);
    float v = (gsum[g * DF + d] / cnt + b2[d]) * Wm[d];
    for (int off = 32; off > 0; off >>= 1) v += __shfl_down(v, off, 64);
    if ((d & 63) == 0) red[d >> 6] = v;
    __syncthreads();
    if (d == 0) out[g] = red[0] + red[1] + bm[0];
}

extern "C" void kernel_launch(void* const* d_in, const int* in_sizes, int n_in,
                              void* d_out, int out_size, void* d_ws, size_t ws_size,
                              hipStream_t stream) {
    const float* x   = (const float*)d_in[0];
    const int*   ei  = (const int*)d_in[1];   // [2, E] flat: first E = src, next E = dst
    const int*   bat = (const int*)d_in[2];
    const float* W1  = (const float*)d_in[3];
    const float* b1  = (const float*)d_in[4];
    const float* W2  = (const float*)d_in[5];
    const float* b2  = (const float*)d_in[6];
    const float* Wm  = (const float*)d_in[7];
    const float* bm  = (const float*)d_in[8];
    float* out = (float*)d_out;

    const int N = NNODES, E = NEDGES, G = NGRAPH;
    const int* src = ei;
    const int* dst = ei + E;

    // workspace carve
    char* base = (char*)d_ws;
    size_t o = 0;
    auto alloc = [&](size_t bytes) { size_t p = o; o = (o + bytes + 255) & ~(size_t)255; return p; };
    int*   deg    = (int*)(base + alloc((size_t)N * 4));
    int*   cursor = (int*)(base + alloc((size_t)N * 4));
    int*   offs   = (int*)(base + alloc((size_t)(N + 1) * 4));
    float* dinv   = (float*)(base + alloc((size_t)N * 4));
    int*   psum   = (int*)(base + alloc((size_t)NB_SCAN * 4));
    int*   csrc   = (int*)(base + alloc((size_t)(E + N) * 4));
    unsigned int* bufH  = (unsigned int*)(base + alloc((size_t)N * DF * 2));  // bf16 H (dinv-scaled)
    unsigned int* bufA16 = (unsigned int*)(base + alloc((size_t)N * DF * 2)); // bf16 layer-1 output
    float* bufB   = (float*)(base + alloc((size_t)N * DF * 4));
    float* gsum   = (float*)(base + alloc((size_t)G * DF * 4));
    float* gcnt   = (float*)(base + alloc((size_t)G * 4));
    unsigned short* wh1 = (unsigned short*)(base + alloc(2048 * 16));
    unsigned short* wl1 = (unsigned short*)(base + alloc(2048 * 16));
    unsigned short* wh2 = (unsigned short*)(base + alloc(2048 * 16));
    unsigned short* wl2 = (unsigned short*)(base + alloc(2048 * 16));
    (void)ws_size;

    hipMemsetAsync(deg, 0, (size_t)N * 4, stream);
    hipMemsetAsync(gsum, 0, (size_t)G * DF * 4, stream);
    hipMemsetAsync(gcnt, 0, (size_t)G * 4, stream);

    // CSR build
    deg_kernel<<<(E + 255) / 256, 256, 0, stream>>>(dst, deg, E);
    scan1_kernel<<<NB_SCAN, 256, 0, stream>>>(deg, psum, dinv, N);
    scan2_kernel<<<1, 64, 0, stream>>>(psum, offs, NB_SCAN, N);
    scan3_kernel<<<NB_SCAN, 256, 0, stream>>>(deg, psum, offs, cursor, csrc, N);
    fill_edges<<<(E + 255) / 256, 256, 0, stream>>>(src, dst, cursor, csrc, E);

    // W prep (tiny)
    wprep_kernel<<<8, 256, 0, stream>>>(W1, wh1, wl1);
    wprep_kernel<<<8, 256, 0, stream>>>(W2, wh2, wl2);

    // layer 1: bufH = bf16(dinv .* (x @ W1)) ; bufA16 = bf16(relu(dinv[v]*sum + b1))
    gemm_mfma<0><<<(N + 63) / 64, 256, 0, stream>>>(x, wh1, wl1, dinv, bufH, N);
    agg_kernel<1, 1><<<N / 4, 256, 0, stream>>>(offs, csrc, dinv, bufH, b1, bufA16);

    // layer 2: bufH = bf16(dinv .* (bufA16 @ W2)) ; bufB = dinv[v]*sum (fp32)
    gemm_mfma<1><<<(N + 63) / 64, 256, 0, stream>>>(bufA16, wh2, wl2, dinv, bufH, N);
    agg_kernel<0, 0><<<N / 4, 256, 0, stream>>>(offs, csrc, dinv, bufH, nullptr, bufB);

    // pool + final
    pool_kernel<<<(N + 127) / 128, 128, 0, stream>>>(bufB, bat, gsum, gcnt, N);
    final_kernel<<<G, 128, 0, stream>>>(gsum, gcnt, b2, Wm, bm, out);
}